// Round 2
// baseline (522.478 us; speedup 1.0000x reference)
//
#include <hip/hip_runtime.h>
#include <hip/hip_bf16.h>
#include <stdint.h>
#include <stddef.h>

#define B_ 4
#define S_ 2048
#define D_ 1024
#define H_ 16
#define HD_ 64
#define NTOK (B_*S_)      // 8192
#define HDIM (H_*HD_)     // 1024

typedef __bf16 bf16_t;
typedef __bf16 bf16x4 __attribute__((ext_vector_type(4)));
typedef __bf16 bf16x8 __attribute__((ext_vector_type(8)));
typedef float floatx4 __attribute__((ext_vector_type(4)));

#define MFMA16(a,b,c) __builtin_amdgcn_mfma_f32_16x16x32_bf16((a),(b),(c),0,0,0)

// ---------------- fp32 -> bf16 bulk convert (5 segments) ----------------
struct Cvt5 { const float* s[5]; bf16_t* d[5]; int n4[5]; };

__global__ __launch_bounds__(256) void cvt5(Cvt5 p) {
    const int z = blockIdx.y;
    const float4* __restrict__ src = (const float4*)p.s[z];
    bf16x4* __restrict__ dst = (bf16x4*)p.d[z];
    const int n4 = p.n4[z];
    for (int i = blockIdx.x * 256 + threadIdx.x; i < n4; i += gridDim.x * 256) {
        const float4 v = src[i];
        dst[i] = (bf16x4){(bf16_t)v.x, (bf16_t)v.y, (bf16_t)v.z, (bf16_t)v.w};
    }
}

// ---------------- NT GEMM: C[m][n] = sum_k A[m][k]*W[n][k] ----------------
// M=8192, N=1024 fixed. bf16 in, fp32 accum.
// MODE 1: bf16 store scattered to [b][h][s][d] (q/k/v projection)
// MODE 2: fp32 store row-major [m][n] (final output)
struct GemmPtrs { const bf16_t* A[3]; const bf16_t* W[3]; void* C[3]; };

template<int MODE>
__global__ __launch_bounds__(256) void gemm_nt(GemmPtrs p, int K) {
    __shared__ bf16_t lA[128*40];   // stride 40 (80 B, 16B-aligned rows)
    __shared__ bf16_t lB[128*40];
    const bf16_t* __restrict__ A = p.A[blockIdx.z];
    const bf16_t* __restrict__ W = p.W[blockIdx.z];
    const int m0 = blockIdx.y * 128;
    const int n0 = blockIdx.x * 128;
    const int t = threadIdx.x;
    const int lane = t & 63;
    const int wave = t >> 6;
    const int wm = wave >> 1;
    const int wn = wave & 1;
    const int l16 = lane & 15;
    const int quad = lane >> 4;

    floatx4 acc[4][4] = {};

    for (int k0 = 0; k0 < K; k0 += 32) {
        for (int c = t; c < 512; c += 256) {
            const int row = c >> 2;
            const int kc = c & 3;
            *(bf16x8*)(&lA[row*40 + kc*8]) =
                *(const bf16x8*)(&A[(size_t)(m0+row)*K + k0 + kc*8]);
            *(bf16x8*)(&lB[row*40 + kc*8]) =
                *(const bf16x8*)(&W[(size_t)(n0+row)*K + k0 + kc*8]);
        }
        __syncthreads();
        bf16x8 af[4], bfr[4];
        #pragma unroll
        for (int i = 0; i < 4; ++i) {
            af[i]  = *(const bf16x8*)(&lA[(wm*64 + i*16 + l16)*40 + quad*8]);
            bfr[i] = *(const bf16x8*)(&lB[(wn*64 + i*16 + l16)*40 + quad*8]);
        }
        #pragma unroll
        for (int i = 0; i < 4; ++i)
            #pragma unroll
            for (int j = 0; j < 4; ++j)
                acc[i][j] = MFMA16(af[i], bfr[j], acc[i][j]);
        __syncthreads();
    }

    // C/D layout: col = lane&15, row = quad*4 + reg
    if (MODE == 1) {
        bf16_t* __restrict__ C = (bf16_t*)p.C[blockIdx.z];
        #pragma unroll
        for (int i = 0; i < 4; ++i) {
            const int mb = m0 + wm*64 + i*16 + quad*4;
            #pragma unroll
            for (int j = 0; j < 4; ++j) {
                const int n = n0 + wn*64 + j*16 + l16;
                const int h = n >> 6, d = n & 63;
                #pragma unroll
                for (int r = 0; r < 4; ++r) {
                    const int m = mb + r;
                    const int b = m >> 11, s = m & (S_-1);
                    C[(((size_t)b*H_ + h)*S_ + s)*HD_ + d] = (bf16_t)acc[i][j][r];
                }
            }
        }
    } else {
        float* __restrict__ C = (float*)p.C[blockIdx.z];
        #pragma unroll
        for (int i = 0; i < 4; ++i) {
            const int mb = m0 + wm*64 + i*16 + quad*4;
            #pragma unroll
            for (int j = 0; j < 4; ++j) {
                const int n = n0 + wn*64 + j*16 + l16;
                #pragma unroll
                for (int r = 0; r < 4; ++r)
                    C[(size_t)(mb + r)*HDIM + n] = acc[i][j][r];
            }
        }
    }
}

// ---------------- in-place RMSNorm + RoPE2D on [b][h][s][d] bf16 ----------
__global__ __launch_bounds__(256) void norm_rope(
    bf16_t* __restrict__ qb, bf16_t* __restrict__ kb, bf16_t* __restrict__ vb,
    const float* __restrict__ cs, const float* __restrict__ sn,
    const float* __restrict__ qscale, const float* __restrict__ kscale) {
    const int wid = (int)((blockIdx.x * 256 + threadIdx.x) >> 6);  // 0..131071
    const int lane = threadIdx.x & 63;
    const int bh = wid >> 11;        // 0..63
    const int s  = wid & (S_-1);
    const int b  = bh >> 4;
    const size_t addr = ((size_t)bh*S_ + s)*HD_ + lane;
    const float q = (float)qb[addr];
    const float k = (float)kb[addr];
    const float v = (float)vb[addr];
    float sq = q*q, sk = k*k, sv = v*v;
    #pragma unroll
    for (int m = 32; m; m >>= 1) {
        sq += __shfl_xor(sq, m);
        sk += __shfl_xor(sk, m);
        sv += __shfl_xor(sv, m);
    }
    const float rq = rsqrtf(sq*(1.f/64.f) + 1e-6f);
    const float rk = rsqrtf(sk*(1.f/64.f) + 1e-6f);
    const float rv = rsqrtf(sv*(1.f/64.f) + 1e-6f);
    float qv = q*rq*qscale[lane];
    float kv = k*rk*kscale[lane];
    const float vv = v*rv;
    const size_t ci = ((size_t)b*S_ + s)*HD_ + lane;
    const float c = cs[ci];
    const float sv_ = sn[ci];
    // rotate_half per 32-dim part: partner = d^16, sign = (d&16) ? +1 : -1
    const float qo = __shfl_xor(qv, 16);
    const float ko = __shfl_xor(kv, 16);
    const float sg = (lane & 16) ? 1.f : -1.f;
    qv = qv*c + sg*qo*sv_;
    kv = kv*c + sg*ko*sv_;
    qb[addr] = (bf16_t)qv;
    kb[addr] = (bf16_t)kv;
    vb[addr] = (bf16_t)vv;
}

// ---------------- flash attention (no 1/sqrt(d), matches reference) -------
// 256 thr = 4 waves; BQ=64 (16 q-rows/wave); K/V tiles of 64 keys.
__global__ __launch_bounds__(256) void flash_attn(
    const bf16_t* __restrict__ qn, const bf16_t* __restrict__ kn,
    const bf16_t* __restrict__ vn, bf16_t* __restrict__ attn_out) {
    __shared__ bf16_t lK[64*72];
    __shared__ bf16_t lVT[64*72];
    __shared__ bf16_t lP[4*16*72];

    const int bh = blockIdx.y;
    const int b  = bh >> 4;
    const int h  = bh & 15;
    const int q0 = blockIdx.x * 64;
    const int t = threadIdx.x;
    const int wave = t >> 6;
    const int lane = t & 63;
    const int l16 = lane & 15;
    const int quad = lane >> 4;

    const bf16_t* Q = qn + (size_t)bh * S_ * HD_;
    const bf16_t* K = kn + (size_t)bh * S_ * HD_;
    const bf16_t* V = vn + (size_t)bh * S_ * HD_;

    const int qrow = q0 + wave*16 + l16;
    const bf16x8 qf0 = *(const bf16x8*)(&Q[(size_t)qrow*HD_ + quad*8]);
    const bf16x8 qf1 = *(const bf16x8*)(&Q[(size_t)qrow*HD_ + 32 + quad*8]);

    floatx4 accO[4] = {};
    float mrow[4] = {-1e30f,-1e30f,-1e30f,-1e30f};
    float lrow[4] = {0.f,0.f,0.f,0.f};

    bf16_t* lPw = &lP[wave*16*72];

    for (int kt = 0; kt < S_; kt += 64) {
        __syncthreads();
        for (int c = t; c < 512; c += 256) {
            const int row = c >> 3, kc = c & 7;
            *(bf16x8*)(&lK[row*72 + kc*8]) =
                *(const bf16x8*)(&K[(size_t)(kt+row)*HD_ + kc*8]);
        }
        {
            const int row = t >> 2;
            const int dc = (t & 3) * 16;
            const bf16x8 v0 = *(const bf16x8*)(&V[(size_t)(kt+row)*HD_ + dc]);
            const bf16x8 v1 = *(const bf16x8*)(&V[(size_t)(kt+row)*HD_ + dc + 8]);
            #pragma unroll
            for (int e = 0; e < 8; ++e) {
                lVT[(dc+e)*72 + row]   = v0[e];
                lVT[(dc+8+e)*72 + row] = v1[e];
            }
        }
        __syncthreads();

        floatx4 sacc[4];
        #pragma unroll
        for (int ct = 0; ct < 4; ++ct) {
            sacc[ct] = (floatx4){0.f,0.f,0.f,0.f};
            const bf16x8 kf0 = *(const bf16x8*)(&lK[(ct*16+l16)*72 + quad*8]);
            const bf16x8 kf1 = *(const bf16x8*)(&lK[(ct*16+l16)*72 + 32 + quad*8]);
            sacc[ct] = MFMA16(qf0, kf0, sacc[ct]);
            sacc[ct] = MFMA16(qf1, kf1, sacc[ct]);
        }

        #pragma unroll
        for (int r = 0; r < 4; ++r) {
            float mx = fmaxf(fmaxf(sacc[0][r], sacc[1][r]), fmaxf(sacc[2][r], sacc[3][r]));
            #pragma unroll
            for (int msk = 1; msk < 16; msk <<= 1)
                mx = fmaxf(mx, __shfl_xor(mx, msk));
            const float mn = fmaxf(mrow[r], mx);
            const float alpha = __expf(mrow[r] - mn);
            mrow[r] = mn;
            float rs = 0.f;
            #pragma unroll
            for (int ct = 0; ct < 4; ++ct) {
                const float pv = __expf(sacc[ct][r] - mn);
                sacc[ct][r] = pv;
                rs += pv;
            }
            #pragma unroll
            for (int msk = 1; msk < 16; msk <<= 1)
                rs += __shfl_xor(rs, msk);
            lrow[r] = lrow[r]*alpha + rs;
            #pragma unroll
            for (int dt = 0; dt < 4; ++dt)
                accO[dt][r] *= alpha;
            #pragma unroll
            for (int ct = 0; ct < 4; ++ct)
                lPw[(quad*4+r)*72 + ct*16 + l16] = (bf16_t)sacc[ct][r];
        }

        const bf16x8 pa0 = *(const bf16x8*)(&lPw[l16*72 + quad*8]);
        const bf16x8 pa1 = *(const bf16x8*)(&lPw[l16*72 + 32 + quad*8]);
        #pragma unroll
        for (int dt = 0; dt < 4; ++dt) {
            const bf16x8 vb0 = *(const bf16x8*)(&lVT[(dt*16+l16)*72 + quad*8]);
            const bf16x8 vb1 = *(const bf16x8*)(&lVT[(dt*16+l16)*72 + 32 + quad*8]);
            accO[dt] = MFMA16(pa0, vb0, accO[dt]);
            accO[dt] = MFMA16(pa1, vb1, accO[dt]);
        }
    }

    #pragma unroll
    for (int dt = 0; dt < 4; ++dt) {
        #pragma unroll
        for (int r = 0; r < 4; ++r) {
            const int srow = q0 + wave*16 + quad*4 + r;
            const float o = accO[dt][r] / lrow[r];
            attn_out[((size_t)b*S_ + srow)*HDIM + h*HD_ + dt*16 + l16] = (bf16_t)o;
        }
    }
}

extern "C" void kernel_launch(void* const* d_in, const int* in_sizes, int n_in,
                              void* d_out, int out_size, void* d_ws, size_t ws_size,
                              hipStream_t stream) {
    (void)in_sizes; (void)n_in; (void)out_size; (void)ws_size;
    const float* X  = (const float*)d_in[0];
    const float* cs = (const float*)d_in[1];
    const float* sn = (const float*)d_in[2];
    // d_in[3] = position_ids: unused by the reference
    const float* wq = (const float*)d_in[4];
    const float* wk = (const float*)d_in[5];
    const float* wv = (const float*)d_in[6];
    const float* wo = (const float*)d_in[7];
    const float* qs = (const float*)d_in[8];
    const float* ks = (const float*)d_in[9];
    float* out = (float*)d_out;

    const size_t PROJ = (size_t)NTOK * HDIM;   // 8.39M elems
    const size_t WSZ  = (size_t)HDIM * D_;     // 1.05M elems
    bf16_t* ws   = (bf16_t*)d_ws;
    bf16_t* Xb   = ws;                          // 16 MB
    bf16_t* wqb  = ws + PROJ;                   // 2 MB each
    bf16_t* wkb  = wqb + WSZ;
    bf16_t* wvb  = wkb + WSZ;
    bf16_t* wob  = wvb + WSZ;
    bf16_t* qb   = wob + WSZ;                   // 16 MB each
    bf16_t* kb   = qb + PROJ;
    bf16_t* vb   = kb + PROJ;
    bf16_t* attn = Xb;                          // Xb dead after gemm1; total ws 72 MB

    Cvt5 cp;
    cp.s[0] = X;  cp.d[0] = Xb;  cp.n4[0] = (int)(PROJ/4);
    cp.s[1] = wq; cp.d[1] = wqb; cp.n4[1] = (int)(WSZ/4);
    cp.s[2] = wk; cp.d[2] = wkb; cp.n4[2] = (int)(WSZ/4);
    cp.s[3] = wv; cp.d[3] = wvb; cp.n4[3] = (int)(WSZ/4);
    cp.s[4] = wo; cp.d[4] = wob; cp.n4[4] = (int)(WSZ/4);
    cvt5<<<dim3(1024, 5), 256, 0, stream>>>(cp);

    GemmPtrs g1;
    g1.A[0] = Xb;  g1.A[1] = Xb;  g1.A[2] = Xb;
    g1.W[0] = wqb; g1.W[1] = wkb; g1.W[2] = wvb;
    g1.C[0] = qb;  g1.C[1] = kb;  g1.C[2] = vb;
    gemm_nt<1><<<dim3(HDIM/128, NTOK/128, 3), 256, 0, stream>>>(g1, D_);

    norm_rope<<<dim3(NTOK*H_/4), 256, 0, stream>>>(qb, kb, vb, cs, sn, qs, ks);

    flash_attn<<<dim3(S_/64, B_*H_), 256, 0, stream>>>(qb, kb, vb, attn);

    GemmPtrs g2;
    g2.A[0] = attn; g2.W[0] = wob; g2.C[0] = out;
    g2.A[1] = attn; g2.W[1] = wob; g2.C[1] = out;
    g2.A[2] = attn; g2.W[2] = wob; g2.C[2] = out;
    gemm_nt<2><<<dim3(HDIM/128, NTOK/128, 1), 256, 0, stream>>>(g2, HDIM);
}

// Round 4
// 439.110 us; speedup vs baseline: 1.1899x; 1.1899x over previous
//
#include <hip/hip_runtime.h>
#include <hip/hip_bf16.h>
#include <stdint.h>
#include <stddef.h>

#define B_ 4
#define S_ 2048
#define D_ 1024
#define H_ 16
#define HD_ 64
#define NTOK (B_*S_)      // 8192
#define HDIM (H_*HD_)     // 1024
#define LOG2E 1.44269504088896f

typedef __bf16 bf16_t;
typedef __bf16 bf16x4 __attribute__((ext_vector_type(4)));
typedef __bf16 bf16x8 __attribute__((ext_vector_type(8)));
typedef float floatx4 __attribute__((ext_vector_type(4)));

#define MFMA16(a,b,c) __builtin_amdgcn_mfma_f32_16x16x32_bf16((a),(b),(c),0,0,0)

// async global->LDS, 16 B per lane; LDS dst must be wave-uniform-base + lane*16
__device__ __forceinline__ void async_cp16(const bf16_t* g, bf16_t* l) {
    typedef __attribute__((address_space(1))) const unsigned int gu32;
    typedef __attribute__((address_space(3))) unsigned int lu32;
    __builtin_amdgcn_global_load_lds((gu32*)g, (lu32*)l, 16, 0, 0);
}

// ---------------- fp32 -> bf16 bulk convert (5 segments) ----------------
struct Cvt5 { const float* s[5]; bf16_t* d[5]; int n4[5]; };

__global__ __launch_bounds__(256) void cvt5(Cvt5 p) {
    const int z = blockIdx.y;
    const float4* __restrict__ src = (const float4*)p.s[z];
    bf16x4* __restrict__ dst = (bf16x4*)p.d[z];
    const int n4 = p.n4[z];
    for (int i = blockIdx.x * 256 + threadIdx.x; i < n4; i += gridDim.x * 256) {
        const float4 v = src[i];
        dst[i] = (bf16x4){(bf16_t)v.x, (bf16_t)v.y, (bf16_t)v.z, (bf16_t)v.w};
    }
}

// ---------------- NT GEMM (m97 structure): C[m][n] = sum_k A[m][k]*W[n][k] --
// MODE 1: bf16 scatter to [b][h][s][d]; MODE 2: fp32 row-major [m][n]
struct GemmPtrs { const bf16_t* A[3]; const bf16_t* W[3]; void* C[3]; };

template<int MODE>
__global__ __launch_bounds__(256) void gemm_nt(GemmPtrs p, int K) {
    __shared__ bf16_t lA[128*32];   // unpadded stride 32 (64 B rows) for global_load_lds
    __shared__ bf16_t lB[128*32];
    const bf16_t* __restrict__ A = p.A[blockIdx.z];
    const bf16_t* __restrict__ W = p.W[blockIdx.z];
    const int m0 = blockIdx.y * 128;
    const int n0 = blockIdx.x * 128;
    const int t = threadIdx.x;
    const int lane = t & 63;
    const int wave = t >> 6;
    const int wm = wave >> 1;
    const int wn = wave & 1;
    const int l16 = lane & 15;
    const int quad = lane >> 4;

    // staging map: wave w, chunk c -> rows w*32+c*16+(lane>>2), kc=lane&3
    const int srow0 = wave*32 + (lane >> 2);
    const int skc   = (lane & 3) * 8;

    floatx4 acc[4][4] = {};

    for (int k0 = 0; k0 < K; k0 += 32) {
        #pragma unroll
        for (int c = 0; c < 2; ++c) {
            const int row = srow0 + c*16;
            async_cp16(&A[(size_t)(m0+row)*K + k0 + skc], &lA[row*32 + skc]);
            async_cp16(&W[(size_t)(n0+row)*K + k0 + skc], &lB[row*32 + skc]);
        }
        __syncthreads();   // compiler drains vmcnt here
        bf16x8 af[4], bfr[4];
        #pragma unroll
        for (int i = 0; i < 4; ++i) {
            af[i]  = *(const bf16x8*)(&lA[(wm*64 + i*16 + l16)*32 + quad*8]);
            bfr[i] = *(const bf16x8*)(&lB[(wn*64 + i*16 + l16)*32 + quad*8]);
        }
        #pragma unroll
        for (int i = 0; i < 4; ++i)
            #pragma unroll
            for (int j = 0; j < 4; ++j)
                acc[i][j] = MFMA16(af[i], bfr[j], acc[i][j]);
        __syncthreads();
    }

    if (MODE == 1) {
        bf16_t* __restrict__ C = (bf16_t*)p.C[blockIdx.z];
        #pragma unroll
        for (int i = 0; i < 4; ++i) {
            const int mb = m0 + wm*64 + i*16 + quad*4;
            #pragma unroll
            for (int j = 0; j < 4; ++j) {
                const int n = n0 + wn*64 + j*16 + l16;
                const int h = n >> 6, d = n & 63;
                #pragma unroll
                for (int r = 0; r < 4; ++r) {
                    const int m = mb + r;
                    const int b = m >> 11, s = m & (S_-1);
                    C[(((size_t)b*H_ + h)*S_ + s)*HD_ + d] = (bf16_t)acc[i][j][r];
                }
            }
        }
    } else {
        float* __restrict__ C = (float*)p.C[blockIdx.z];
        #pragma unroll
        for (int i = 0; i < 4; ++i) {
            const int mb = m0 + wm*64 + i*16 + quad*4;
            #pragma unroll
            for (int j = 0; j < 4; ++j) {
                const int n = n0 + wn*64 + j*16 + l16;
                #pragma unroll
                for (int r = 0; r < 4; ++r)
                    C[(size_t)(mb + r)*HDIM + n] = acc[i][j][r];
            }
        }
    }
}

// ------ RMSNorm + RoPE2D in place on q,k; v normed + transposed to [bh][d][s]
// q additionally scaled by log2(e) so flash can use raw v_exp_f32 (exp2).
// grid (S_/64, B*H), block 256 = 4 waves x 16 tokens.
__global__ __launch_bounds__(256) void norm_rope(
    bf16_t* __restrict__ qb, bf16_t* __restrict__ kb,
    const bf16_t* __restrict__ vb, bf16_t* __restrict__ vt,
    const float* __restrict__ cs, const float* __restrict__ sn,
    const float* __restrict__ qscale, const float* __restrict__ kscale) {
    __shared__ bf16_t lv[64*65];
    const int bh = blockIdx.y;
    const int b  = bh >> 4;
    const int s0 = blockIdx.x * 64;
    const int t = threadIdx.x;
    const int wave = t >> 6;
    const int lane = t & 63;
    const float qsc = qscale[lane] * LOG2E;
    const float ksc = kscale[lane];
    const float sg = (lane & 16) ? 1.f : -1.f;

    for (int i = 0; i < 16; ++i) {
        const int s = s0 + wave*16 + i;
        const size_t addr = ((size_t)bh*S_ + s)*HD_ + lane;
        const float q = (float)qb[addr];
        const float k = (float)kb[addr];
        const float v = (float)vb[addr];
        float sq = q*q, sk = k*k, sv = v*v;
        #pragma unroll
        for (int m = 32; m; m >>= 1) {
            sq += __shfl_xor(sq, m);
            sk += __shfl_xor(sk, m);
            sv += __shfl_xor(sv, m);
        }
        float qv = q * rsqrtf(sq*(1.f/64.f) + 1e-6f) * qsc;
        float kv = k * rsqrtf(sk*(1.f/64.f) + 1e-6f) * ksc;
        const float vv = v * rsqrtf(sv*(1.f/64.f) + 1e-6f);
        const size_t ci = ((size_t)b*S_ + s)*HD_ + lane;
        const float c = cs[ci];
        const float sn_ = sn[ci];
        const float qo = __shfl_xor(qv, 16);
        const float ko = __shfl_xor(kv, 16);
        qv = qv*c + sg*qo*sn_;
        kv = kv*c + sg*ko*sn_;
        qb[addr] = (bf16_t)qv;
        kb[addr] = (bf16_t)kv;
        lv[(wave*16 + i)*65 + lane] = (bf16_t)vv;
    }
    __syncthreads();
    // write vt[bh][d][s0..s0+63]: thread t -> d = t>>2, 16 s each
    const int d = t >> 2;
    const int sc = (t & 3) * 16;
    bf16x8 o0, o1;
    #pragma unroll
    for (int e = 0; e < 8; ++e) {
        o0[e] = lv[(sc + e)*65 + d];
        o1[e] = lv[(sc + 8 + e)*65 + d];
    }
    bf16_t* dst = &vt[((size_t)bh*HD_ + d)*S_ + s0 + sc];
    *(bf16x8*)(dst)     = o0;
    *(bf16x8*)(dst + 8) = o1;
}

// ---------------- flash attention v2 -------------------------------------
// 512 thr = 8 waves, BQ=128 (16 q-rows/wave), 64-key tiles, register-prefetch
// double buffering, V pre-transposed ([bh][d][s]), exp2-domain softmax.
__global__ __launch_bounds__(512, 4) void flash_attn(
    const bf16_t* __restrict__ qn, const bf16_t* __restrict__ kn,
    const bf16_t* __restrict__ vt, bf16_t* __restrict__ attn_out) {
    __shared__ bf16_t lK[64*72];    // [key][d]
    __shared__ bf16_t lV[64*72];    // [d][key]
    __shared__ bf16_t lP[8*16*72];  // per-wave [16 q][64 key]

    const int bh = blockIdx.y;
    const int b  = bh >> 4;
    const int h  = bh & 15;
    const int q0 = blockIdx.x * 128;
    const int t = threadIdx.x;
    const int wave = t >> 6;
    const int lane = t & 63;
    const int l16 = lane & 15;
    const int quad = lane >> 4;
    const floatx4 fzero = {0.f, 0.f, 0.f, 0.f};

    const bf16_t* Q  = qn + (size_t)bh * S_ * HD_;
    const bf16_t* K  = kn + (size_t)bh * S_ * HD_;
    const bf16_t* Vt = vt + (size_t)bh * HD_ * S_;

    const int qrow = q0 + wave*16 + l16;
    const bf16x8 qf0 = *(const bf16x8*)(&Q[(size_t)qrow*HD_ + quad*8]);
    const bf16x8 qf1 = *(const bf16x8*)(&Q[(size_t)qrow*HD_ + 32 + quad*8]);

    floatx4 accO[4] = {};
    float mrow[4] = {-1e30f,-1e30f,-1e30f,-1e30f};
    float lrow[4] = {0.f,0.f,0.f,0.f};

    bf16_t* lPw = &lP[wave*16*72];

    // staging map: thread t covers K[key=t>>3][d=(t&7)*8] and Vt[d=t>>3][key=(t&7)*8]
    const int srow = t >> 3;
    const int skc  = (t & 7) * 8;

    bf16x8 kpre = *(const bf16x8*)(&K[(size_t)srow*HD_ + skc]);
    bf16x8 vpre = *(const bf16x8*)(&Vt[(size_t)srow*S_ + skc]);

    for (int kt = 0; kt < S_; kt += 64) {
        __syncthreads();            // all waves done reading lK/lV
        *(bf16x8*)(&lK[srow*72 + skc]) = kpre;
        *(bf16x8*)(&lV[srow*72 + skc]) = vpre;
        __syncthreads();            // staging visible
        {   // prefetch next tile (clamped on last iter; overlaps with compute)
            const int ktn = (kt + 64 < S_) ? kt + 64 : kt;
            kpre = *(const bf16x8*)(&K[(size_t)(ktn+srow)*HD_ + skc]);
            vpre = *(const bf16x8*)(&Vt[(size_t)srow*S_ + ktn + skc]);
        }

        // S = Q K^T
        floatx4 sacc[4];
        #pragma unroll
        for (int ct = 0; ct < 4; ++ct) {
            const bf16x8 kf0 = *(const bf16x8*)(&lK[(ct*16+l16)*72 + quad*8]);
            const bf16x8 kf1 = *(const bf16x8*)(&lK[(ct*16+l16)*72 + 32 + quad*8]);
            sacc[ct] = MFMA16(qf0, kf0, fzero);
            sacc[ct] = MFMA16(qf1, kf1, sacc[ct]);
        }

        // online softmax (log2 domain; scores already scaled by log2e via Q)
        #pragma unroll
        for (int r = 0; r < 4; ++r) {
            float mx = fmaxf(fmaxf(sacc[0][r], sacc[1][r]), fmaxf(sacc[2][r], sacc[3][r]));
            #pragma unroll
            for (int msk = 1; msk < 16; msk <<= 1)
                mx = fmaxf(mx, __shfl_xor(mx, msk));
            const float mn = fmaxf(mrow[r], mx);
            const float alpha = __builtin_amdgcn_exp2f(mrow[r] - mn);
            mrow[r] = mn;
            float rs = 0.f;
            #pragma unroll
            for (int ct = 0; ct < 4; ++ct) {
                const float pv = __builtin_amdgcn_exp2f(sacc[ct][r] - mn);
                sacc[ct][r] = pv;
                rs += pv;
            }
            #pragma unroll
            for (int msk = 1; msk < 16; msk <<= 1)
                rs += __shfl_xor(rs, msk);
            lrow[r] = lrow[r]*alpha + rs;
            #pragma unroll
            for (int dt = 0; dt < 4; ++dt)
                accO[dt][r] *= alpha;
            #pragma unroll
            for (int ct = 0; ct < 4; ++ct)
                lPw[(quad*4+r)*72 + ct*16 + l16] = (bf16_t)sacc[ct][r];
        }

        // O += P V
        const bf16x8 pa0 = *(const bf16x8*)(&lPw[l16*72 + quad*8]);
        const bf16x8 pa1 = *(const bf16x8*)(&lPw[l16*72 + 32 + quad*8]);
        #pragma unroll
        for (int dt = 0; dt < 4; ++dt) {
            const bf16x8 vb0 = *(const bf16x8*)(&lV[(dt*16+l16)*72 + quad*8]);
            const bf16x8 vb1 = *(const bf16x8*)(&lV[(dt*16+l16)*72 + 32 + quad*8]);
            accO[dt] = MFMA16(pa0, vb0, accO[dt]);
            accO[dt] = MFMA16(pa1, vb1, accO[dt]);
        }
    }

    #pragma unroll
    for (int dt = 0; dt < 4; ++dt) {
        #pragma unroll
        for (int r = 0; r < 4; ++r) {
            const int srw = q0 + wave*16 + quad*4 + r;
            const float o = accO[dt][r] / lrow[r];
            attn_out[((size_t)b*S_ + srw)*HDIM + h*HD_ + dt*16 + l16] = (bf16_t)o;
        }
    }
}

extern "C" void kernel_launch(void* const* d_in, const int* in_sizes, int n_in,
                              void* d_out, int out_size, void* d_ws, size_t ws_size,
                              hipStream_t stream) {
    (void)in_sizes; (void)n_in; (void)out_size; (void)ws_size;
    const float* X  = (const float*)d_in[0];
    const float* cs = (const float*)d_in[1];
    const float* sn = (const float*)d_in[2];
    const float* wq = (const float*)d_in[4];
    const float* wk = (const float*)d_in[5];
    const float* wv = (const float*)d_in[6];
    const float* wo = (const float*)d_in[7];
    const float* qs = (const float*)d_in[8];
    const float* ks = (const float*)d_in[9];
    float* out = (float*)d_out;

    const size_t PROJ = (size_t)NTOK * HDIM;   // 8.39M elems (16 MB bf16)
    const size_t WSZ  = (size_t)HDIM * D_;
    bf16_t* ws   = (bf16_t*)d_ws;
    bf16_t* Xb   = ws;                 // 16 MB; dead after gemm1 -> reused as vt
    bf16_t* wqb  = ws + PROJ;
    bf16_t* wkb  = wqb + WSZ;
    bf16_t* wvb  = wkb + WSZ;
    bf16_t* wob  = wvb + WSZ;
    bf16_t* qb   = wob + WSZ;
    bf16_t* kb   = qb + PROJ;
    bf16_t* vb   = kb + PROJ;          // dead after norm_rope -> reused as attn
    bf16_t* vt   = Xb;
    bf16_t* attn = vb;                 // total ws: 72 MB

    Cvt5 cp;
    cp.s[0] = X;  cp.d[0] = Xb;  cp.n4[0] = (int)(PROJ/4);
    cp.s[1] = wq; cp.d[1] = wqb; cp.n4[1] = (int)(WSZ/4);
    cp.s[2] = wk; cp.d[2] = wkb; cp.n4[2] = (int)(WSZ/4);
    cp.s[3] = wv; cp.d[3] = wvb; cp.n4[3] = (int)(WSZ/4);
    cp.s[4] = wo; cp.d[4] = wob; cp.n4[4] = (int)(WSZ/4);
    cvt5<<<dim3(1024, 5), 256, 0, stream>>>(cp);

    GemmPtrs g1;
    g1.A[0] = Xb;  g1.A[1] = Xb;  g1.A[2] = Xb;
    g1.W[0] = wqb; g1.W[1] = wkb; g1.W[2] = wvb;
    g1.C[0] = qb;  g1.C[1] = kb;  g1.C[2] = vb;
    gemm_nt<1><<<dim3(HDIM/128, NTOK/128, 3), 256, 0, stream>>>(g1, D_);

    norm_rope<<<dim3(S_/64, B_*H_), 256, 0, stream>>>(qb, kb, vb, vt, cs, sn, qs, ks);

    flash_attn<<<dim3(S_/128, B_*H_), 512, 0, stream>>>(qb, kb, vt, attn);

    GemmPtrs g2;
    g2.A[0] = attn; g2.W[0] = wob; g2.C[0] = out;
    g2.A[1] = attn; g2.W[1] = wob; g2.C[1] = out;
    g2.A[2] = attn; g2.W[2] = wob; g2.C[2] = out;
    gemm_nt<2><<<dim3(HDIM/128, NTOK/128, 1), 256, 0, stream>>>(g2, HDIM);
}

// Round 5
// 404.827 us; speedup vs baseline: 1.2906x; 1.0847x over previous
//
#include <hip/hip_runtime.h>
#include <hip/hip_bf16.h>
#include <stdint.h>
#include <stddef.h>

#define B_ 4
#define S_ 2048
#define D_ 1024
#define H_ 16
#define HD_ 64
#define NTOK (B_*S_)      // 8192
#define HDIM (H_*HD_)     // 1024
#define LOG2E 1.44269504088896f

typedef __bf16 bf16_t;
typedef __bf16 bf16x4 __attribute__((ext_vector_type(4)));
typedef __bf16 bf16x8 __attribute__((ext_vector_type(8)));
typedef float floatx4 __attribute__((ext_vector_type(4)));

#define MFMA16(a,b,c) __builtin_amdgcn_mfma_f32_16x16x32_bf16((a),(b),(c),0,0,0)

// async global->LDS, 16 B per lane; LDS dst must be wave-uniform-base + lane*16
__device__ __forceinline__ void async_cp16(const bf16_t* g, bf16_t* l) {
    typedef __attribute__((address_space(1))) const unsigned int gu32;
    typedef __attribute__((address_space(3))) unsigned int lu32;
    __builtin_amdgcn_global_load_lds((gu32*)g, (lu32*)l, 16, 0, 0);
}

// ---------------- fp32 -> bf16 bulk convert (5 segments) ----------------
struct Cvt5 { const float* s[5]; bf16_t* d[5]; int n4[5]; };

__global__ __launch_bounds__(256) void cvt5(Cvt5 p) {
    const int z = blockIdx.y;
    const float4* __restrict__ src = (const float4*)p.s[z];
    bf16x4* __restrict__ dst = (bf16x4*)p.d[z];
    const int n4 = p.n4[z];
    for (int i = blockIdx.x * 256 + threadIdx.x; i < n4; i += gridDim.x * 256) {
        const float4 v = src[i];
        dst[i] = (bf16x4){(bf16_t)v.x, (bf16_t)v.y, (bf16_t)v.z, (bf16_t)v.w};
    }
}

// ---------------- NT GEMM (m97 structure): C[m][n] = sum_k A[m][k]*W[n][k] --
// MODE 1: bf16 scatter to [b][h][s][d]; MODE 2: fp32 row-major [m][n]
struct GemmPtrs { const bf16_t* A[3]; const bf16_t* W[3]; void* C[3]; };

template<int MODE>
__global__ __launch_bounds__(256) void gemm_nt(GemmPtrs p, int K) {
    __shared__ bf16_t lA[128*32];   // unpadded stride 32 (64 B rows) for global_load_lds
    __shared__ bf16_t lB[128*32];
    const bf16_t* __restrict__ A = p.A[blockIdx.z];
    const bf16_t* __restrict__ W = p.W[blockIdx.z];
    const int m0 = blockIdx.y * 128;
    const int n0 = blockIdx.x * 128;
    const int t = threadIdx.x;
    const int lane = t & 63;
    const int wave = t >> 6;
    const int wm = wave >> 1;
    const int wn = wave & 1;
    const int l16 = lane & 15;
    const int quad = lane >> 4;

    const int srow0 = wave*32 + (lane >> 2);
    const int skc   = (lane & 3) * 8;

    floatx4 acc[4][4] = {};

    for (int k0 = 0; k0 < K; k0 += 32) {
        #pragma unroll
        for (int c = 0; c < 2; ++c) {
            const int row = srow0 + c*16;
            async_cp16(&A[(size_t)(m0+row)*K + k0 + skc], &lA[row*32 + skc]);
            async_cp16(&W[(size_t)(n0+row)*K + k0 + skc], &lB[row*32 + skc]);
        }
        __syncthreads();   // compiler drains vmcnt here
        bf16x8 af[4], bfr[4];
        #pragma unroll
        for (int i = 0; i < 4; ++i) {
            af[i]  = *(const bf16x8*)(&lA[(wm*64 + i*16 + l16)*32 + quad*8]);
            bfr[i] = *(const bf16x8*)(&lB[(wn*64 + i*16 + l16)*32 + quad*8]);
        }
        #pragma unroll
        for (int i = 0; i < 4; ++i)
            #pragma unroll
            for (int j = 0; j < 4; ++j)
                acc[i][j] = MFMA16(af[i], bfr[j], acc[i][j]);
        __syncthreads();
    }

    if (MODE == 1) {
        bf16_t* __restrict__ C = (bf16_t*)p.C[blockIdx.z];
        #pragma unroll
        for (int i = 0; i < 4; ++i) {
            const int mb = m0 + wm*64 + i*16 + quad*4;
            #pragma unroll
            for (int j = 0; j < 4; ++j) {
                const int n = n0 + wn*64 + j*16 + l16;
                const int h = n >> 6, d = n & 63;
                #pragma unroll
                for (int r = 0; r < 4; ++r) {
                    const int m = mb + r;
                    const int b = m >> 11, s = m & (S_-1);
                    C[(((size_t)b*H_ + h)*S_ + s)*HD_ + d] = (bf16_t)acc[i][j][r];
                }
            }
        }
    } else {
        float* __restrict__ C = (float*)p.C[blockIdx.z];
        #pragma unroll
        for (int i = 0; i < 4; ++i) {
            const int mb = m0 + wm*64 + i*16 + quad*4;
            #pragma unroll
            for (int j = 0; j < 4; ++j) {
                const int n = n0 + wn*64 + j*16 + l16;
                #pragma unroll
                for (int r = 0; r < 4; ++r)
                    C[(size_t)(mb + r)*HDIM + n] = acc[i][j][r];
            }
        }
    }
}

// ------ RMSNorm + RoPE2D in place on q,k; v normed + transposed to [bh][d][s]
// q additionally scaled by log2(e) so flash can use raw v_exp_f32 (exp2).
__global__ __launch_bounds__(256) void norm_rope(
    bf16_t* __restrict__ qb, bf16_t* __restrict__ kb,
    const bf16_t* __restrict__ vb, bf16_t* __restrict__ vt,
    const float* __restrict__ cs, const float* __restrict__ sn,
    const float* __restrict__ qscale, const float* __restrict__ kscale) {
    __shared__ bf16_t lv[64*65];
    const int bh = blockIdx.y;
    const int b  = bh >> 4;
    const int s0 = blockIdx.x * 64;
    const int t = threadIdx.x;
    const int wave = t >> 6;
    const int lane = t & 63;
    const float qsc = qscale[lane] * LOG2E;
    const float ksc = kscale[lane];
    const float sg = (lane & 16) ? 1.f : -1.f;

    for (int i = 0; i < 16; ++i) {
        const int s = s0 + wave*16 + i;
        const size_t addr = ((size_t)bh*S_ + s)*HD_ + lane;
        const float q = (float)qb[addr];
        const float k = (float)kb[addr];
        const float v = (float)vb[addr];
        float sq = q*q, sk = k*k, sv = v*v;
        #pragma unroll
        for (int m = 32; m; m >>= 1) {
            sq += __shfl_xor(sq, m);
            sk += __shfl_xor(sk, m);
            sv += __shfl_xor(sv, m);
        }
        float qv = q * rsqrtf(sq*(1.f/64.f) + 1e-6f) * qsc;
        float kv = k * rsqrtf(sk*(1.f/64.f) + 1e-6f) * ksc;
        const float vv = v * rsqrtf(sv*(1.f/64.f) + 1e-6f);
        const size_t ci = ((size_t)b*S_ + s)*HD_ + lane;
        const float c = cs[ci];
        const float sn_ = sn[ci];
        const float qo = __shfl_xor(qv, 16);
        const float ko = __shfl_xor(kv, 16);
        qv = qv*c + sg*qo*sn_;
        kv = kv*c + sg*ko*sn_;
        qb[addr] = (bf16_t)qv;
        kb[addr] = (bf16_t)kv;
        lv[(wave*16 + i)*65 + lane] = (bf16_t)vv;
    }
    __syncthreads();
    const int d = t >> 2;
    const int sc = (t & 3) * 16;
    bf16x8 o0, o1;
    #pragma unroll
    for (int e = 0; e < 8; ++e) {
        o0[e] = lv[(sc + e)*65 + d];
        o1[e] = lv[(sc + 8 + e)*65 + d];
    }
    bf16_t* dst = &vt[((size_t)bh*HD_ + d)*S_ + s0 + sc];
    *(bf16x8*)(dst)     = o0;
    *(bf16x8*)(dst + 8) = o1;
}

// ---------------- flash attention v3 -------------------------------------
// No online max: scores bounded (|s|<~50 in log2 domain), so seed the QK
// accumulator with -46 and exp2 directly; the 2^-46 scale cancels in O/l.
// Row-sum l computed by an extra MFMA against a ones-column B fragment.
// 512 thr = 8 waves, BQ=128, 64-key tiles, register-prefetch double buffer.
__global__ __launch_bounds__(512, 4) void flash_attn(
    const bf16_t* __restrict__ qn, const bf16_t* __restrict__ kn,
    const bf16_t* __restrict__ vt, bf16_t* __restrict__ attn_out) {
    __shared__ bf16_t lK[64*72];    // [key][d]
    __shared__ bf16_t lV[64*72];    // [d][key]
    __shared__ bf16_t lP[8*16*76];  // per-wave [16 q][64 key], stride 76 = conflict-free b16 stores

    const int bh = blockIdx.y;
    const int b  = bh >> 4;
    const int h  = bh & 15;
    const int q0 = blockIdx.x * 128;
    const int t = threadIdx.x;
    const int wave = t >> 6;
    const int lane = t & 63;
    const int l16 = lane & 15;
    const int quad = lane >> 4;
    const floatx4 finit = {-46.f, -46.f, -46.f, -46.f};

    const bf16_t* Q  = qn + (size_t)bh * S_ * HD_;
    const bf16_t* K  = kn + (size_t)bh * S_ * HD_;
    const bf16_t* Vt = vt + (size_t)bh * HD_ * S_;

    const int qrow = q0 + wave*16 + l16;
    const bf16x8 qf0 = *(const bf16x8*)(&Q[(size_t)qrow*HD_ + quad*8]);
    const bf16x8 qf1 = *(const bf16x8*)(&Q[(size_t)qrow*HD_ + 32 + quad*8]);

    // ones-column B fragment: col 0 of the synthetic V-extension is 1, rest 0
    bf16x8 onesf;
    {
        const bf16_t oz = (l16 == 0) ? (bf16_t)1.f : (bf16_t)0.f;
        #pragma unroll
        for (int e = 0; e < 8; ++e) onesf[e] = oz;
    }

    floatx4 accO[4] = {};
    floatx4 accL = {};

    bf16_t* lPw = &lP[wave*16*76];

    const int srow = t >> 3;
    const int skc  = (t & 7) * 8;

    bf16x8 kpre = *(const bf16x8*)(&K[(size_t)srow*HD_ + skc]);
    bf16x8 vpre = *(const bf16x8*)(&Vt[(size_t)srow*S_ + skc]);

    for (int kt = 0; kt < S_; kt += 64) {
        __syncthreads();
        *(bf16x8*)(&lK[srow*72 + skc]) = kpre;
        *(bf16x8*)(&lV[srow*72 + skc]) = vpre;
        __syncthreads();
        {
            const int ktn = (kt + 64 < S_) ? kt + 64 : kt;
            kpre = *(const bf16x8*)(&K[(size_t)(ktn+srow)*HD_ + skc]);
            vpre = *(const bf16x8*)(&Vt[(size_t)srow*S_ + ktn + skc]);
        }

        // S = Q K^T - 46  (log2 domain; Q carries log2e)
        floatx4 sacc[4];
        #pragma unroll
        for (int ct = 0; ct < 4; ++ct) {
            const bf16x8 kf0 = *(const bf16x8*)(&lK[(ct*16+l16)*72 + quad*8]);
            const bf16x8 kf1 = *(const bf16x8*)(&lK[(ct*16+l16)*72 + 32 + quad*8]);
            sacc[ct] = MFMA16(qf0, kf0, finit);
            sacc[ct] = MFMA16(qf1, kf1, sacc[ct]);
        }

        // P = exp2(S) -> per-wave LDS (row = quad*4+r, col = ct*16+l16)
        #pragma unroll
        for (int ct = 0; ct < 4; ++ct)
            #pragma unroll
            for (int r = 0; r < 4; ++r)
                lPw[(quad*4+r)*76 + ct*16 + l16] =
                    (bf16_t)__builtin_amdgcn_exp2f(sacc[ct][r]);

        // O += P V ; L += P * ones   (A from lPw, B from lV / synthetic)
        const bf16x8 pa0 = *(const bf16x8*)(&lPw[l16*76 + quad*8]);
        const bf16x8 pa1 = *(const bf16x8*)(&lPw[l16*76 + 32 + quad*8]);
        #pragma unroll
        for (int dt = 0; dt < 4; ++dt) {
            const bf16x8 vb0 = *(const bf16x8*)(&lV[(dt*16+l16)*72 + quad*8]);
            const bf16x8 vb1 = *(const bf16x8*)(&lV[(dt*16+l16)*72 + 32 + quad*8]);
            accO[dt] = MFMA16(pa0, vb0, accO[dt]);
            accO[dt] = MFMA16(pa1, vb1, accO[dt]);
        }
        accL = MFMA16(pa0, onesf, accL);
        accL = MFMA16(pa1, onesf, accL);
    }

    // epilogue: l for row quad*4+r sits at col 0 -> lane quad*16; broadcast
    #pragma unroll
    for (int r = 0; r < 4; ++r) {
        const float lr = __shfl(accL[r], lane & 48);
        const float inv = 1.f / lr;
        const int srw = q0 + wave*16 + quad*4 + r;
        #pragma unroll
        for (int dt = 0; dt < 4; ++dt) {
            attn_out[((size_t)b*S_ + srw)*HDIM + h*HD_ + dt*16 + l16] =
                (bf16_t)(accO[dt][r] * inv);
        }
    }
}

extern "C" void kernel_launch(void* const* d_in, const int* in_sizes, int n_in,
                              void* d_out, int out_size, void* d_ws, size_t ws_size,
                              hipStream_t stream) {
    (void)in_sizes; (void)n_in; (void)out_size; (void)ws_size;
    const float* X  = (const float*)d_in[0];
    const float* cs = (const float*)d_in[1];
    const float* sn = (const float*)d_in[2];
    const float* wq = (const float*)d_in[4];
    const float* wk = (const float*)d_in[5];
    const float* wv = (const float*)d_in[6];
    const float* wo = (const float*)d_in[7];
    const float* qs = (const float*)d_in[8];
    const float* ks = (const float*)d_in[9];
    float* out = (float*)d_out;

    const size_t PROJ = (size_t)NTOK * HDIM;
    const size_t WSZ  = (size_t)HDIM * D_;
    bf16_t* ws   = (bf16_t*)d_ws;
    bf16_t* Xb   = ws;                 // dead after gemm1 -> reused as vt
    bf16_t* wqb  = ws + PROJ;
    bf16_t* wkb  = wqb + WSZ;
    bf16_t* wvb  = wkb + WSZ;
    bf16_t* wob  = wvb + WSZ;
    bf16_t* qb   = wob + WSZ;
    bf16_t* kb   = qb + PROJ;
    bf16_t* vb   = kb + PROJ;          // dead after norm_rope -> reused as attn
    bf16_t* vt   = Xb;
    bf16_t* attn = vb;                 // total ws: 72 MB

    Cvt5 cp;
    cp.s[0] = X;  cp.d[0] = Xb;  cp.n4[0] = (int)(PROJ/4);
    cp.s[1] = wq; cp.d[1] = wqb; cp.n4[1] = (int)(WSZ/4);
    cp.s[2] = wk; cp.d[2] = wkb; cp.n4[2] = (int)(WSZ/4);
    cp.s[3] = wv; cp.d[3] = wvb; cp.n4[3] = (int)(WSZ/4);
    cp.s[4] = wo; cp.d[4] = wob; cp.n4[4] = (int)(WSZ/4);
    cvt5<<<dim3(1024, 5), 256, 0, stream>>>(cp);

    GemmPtrs g1;
    g1.A[0] = Xb;  g1.A[1] = Xb;  g1.A[2] = Xb;
    g1.W[0] = wqb; g1.W[1] = wkb; g1.W[2] = wvb;
    g1.C[0] = qb;  g1.C[1] = kb;  g1.C[2] = vb;
    gemm_nt<1><<<dim3(HDIM/128, NTOK/128, 3), 256, 0, stream>>>(g1, D_);

    norm_rope<<<dim3(S_/64, B_*H_), 256, 0, stream>>>(qb, kb, vb, vt, cs, sn, qs, ks);

    flash_attn<<<dim3(S_/128, B_*H_), 512, 0, stream>>>(qb, kb, vt, attn);

    GemmPtrs g2;
    g2.A[0] = attn; g2.W[0] = wob; g2.C[0] = out;
    g2.A[1] = attn; g2.W[1] = wob; g2.C[1] = out;
    g2.A[2] = attn; g2.W[2] = wob; g2.C[2] = out;
    gemm_nt<2><<<dim3(HDIM/128, NTOK/128, 1), 256, 0, stream>>>(g2, HDIM);
}

// Round 6
// 359.367 us; speedup vs baseline: 1.4539x; 1.1265x over previous
//
#include <hip/hip_runtime.h>
#include <hip/hip_bf16.h>
#include <stdint.h>
#include <stddef.h>

#define B_ 4
#define S_ 2048
#define D_ 1024
#define H_ 16
#define HD_ 64
#define NTOK (B_*S_)      // 8192
#define HDIM (H_*HD_)     // 1024
#define LOG2E 1.44269504088896f

typedef __bf16 bf16_t;
typedef __bf16 bf16x4 __attribute__((ext_vector_type(4)));
typedef __bf16 bf16x8 __attribute__((ext_vector_type(8)));
typedef float floatx4 __attribute__((ext_vector_type(4)));

#define MFMA16(a,b,c) __builtin_amdgcn_mfma_f32_16x16x32_bf16((a),(b),(c),0,0,0)

// async global->LDS, 16 B per lane; LDS dst must be wave-uniform-base + lane*16
__device__ __forceinline__ void async_cp16(const bf16_t* g, bf16_t* l) {
    typedef __attribute__((address_space(1))) const unsigned int gu32;
    typedef __attribute__((address_space(3))) unsigned int lu32;
    __builtin_amdgcn_global_load_lds((gu32*)g, (lu32*)l, 16, 0, 0);
}

// ---------------- fp32 -> bf16 bulk convert (5 segments) ----------------
struct Cvt5 { const float* s[5]; bf16_t* d[5]; int n4[5]; };

__global__ __launch_bounds__(256) void cvt5(Cvt5 p) {
    const int z = blockIdx.y;
    const float4* __restrict__ src = (const float4*)p.s[z];
    bf16x4* __restrict__ dst = (bf16x4*)p.d[z];
    const int n4 = p.n4[z];
    for (int i = blockIdx.x * 256 + threadIdx.x; i < n4; i += gridDim.x * 256) {
        const float4 v = src[i];
        dst[i] = (bf16x4){(bf16_t)v.x, (bf16_t)v.y, (bf16_t)v.z, (bf16_t)v.w};
    }
}

// ---------------- NT GEMM, BK=64 (dual stride-32 buffers) -----------------
// C[m][n] = sum_k A[m][k]*W[n][k]; M=8192, N=1024, K multiple of 64.
// MODE 1: bf16 scatter to [b][h][s][d]; MODE 2: fp32 row-major [m][n]
struct GemmPtrs { const bf16_t* A[3]; const bf16_t* W[3]; void* C[3]; };

template<int MODE>
__global__ __launch_bounds__(256, 3) void gemm_nt(GemmPtrs p, int K) {
    __shared__ bf16_t lA0[128*32], lA1[128*32];   // k 0..31 / 32..63 of the 64-k tile
    __shared__ bf16_t lB0[128*32], lB1[128*32];
    const bf16_t* __restrict__ A = p.A[blockIdx.z];
    const bf16_t* __restrict__ W = p.W[blockIdx.z];
    const int m0 = blockIdx.y * 128;
    const int n0 = blockIdx.x * 128;
    const int t = threadIdx.x;
    const int lane = t & 63;
    const int wave = t >> 6;
    const int wm = wave >> 1;
    const int wn = wave & 1;
    const int l16 = lane & 15;
    const int quad = lane >> 4;

    const int srow0 = wave*32 + (lane >> 2);
    const int skc   = (lane & 3) * 8;

    floatx4 acc[4][4] = {};

    for (int k0 = 0; k0 < K; k0 += 64) {
        #pragma unroll
        for (int c = 0; c < 2; ++c) {
            const int row = srow0 + c*16;
            const size_t ao = (size_t)(m0+row)*K + k0 + skc;
            const size_t wo = (size_t)(n0+row)*K + k0 + skc;
            async_cp16(&A[ao],      &lA0[row*32 + skc]);
            async_cp16(&A[ao + 32], &lA1[row*32 + skc]);
            async_cp16(&W[wo],      &lB0[row*32 + skc]);
            async_cp16(&W[wo + 32], &lB1[row*32 + skc]);
        }
        __syncthreads();   // compiler drains vmcnt here
        {
            bf16x8 af[4], bfr[4];
            #pragma unroll
            for (int i = 0; i < 4; ++i) {
                af[i]  = *(const bf16x8*)(&lA0[(wm*64 + i*16 + l16)*32 + quad*8]);
                bfr[i] = *(const bf16x8*)(&lB0[(wn*64 + i*16 + l16)*32 + quad*8]);
            }
            #pragma unroll
            for (int i = 0; i < 4; ++i)
                #pragma unroll
                for (int j = 0; j < 4; ++j)
                    acc[i][j] = MFMA16(af[i], bfr[j], acc[i][j]);
        }
        {
            bf16x8 af[4], bfr[4];
            #pragma unroll
            for (int i = 0; i < 4; ++i) {
                af[i]  = *(const bf16x8*)(&lA1[(wm*64 + i*16 + l16)*32 + quad*8]);
                bfr[i] = *(const bf16x8*)(&lB1[(wn*64 + i*16 + l16)*32 + quad*8]);
            }
            #pragma unroll
            for (int i = 0; i < 4; ++i)
                #pragma unroll
                for (int j = 0; j < 4; ++j)
                    acc[i][j] = MFMA16(af[i], bfr[j], acc[i][j]);
        }
        __syncthreads();
    }

    if (MODE == 1) {
        bf16_t* __restrict__ C = (bf16_t*)p.C[blockIdx.z];
        #pragma unroll
        for (int i = 0; i < 4; ++i) {
            const int mb = m0 + wm*64 + i*16 + quad*4;
            #pragma unroll
            for (int j = 0; j < 4; ++j) {
                const int n = n0 + wn*64 + j*16 + l16;
                const int h = n >> 6, d = n & 63;
                #pragma unroll
                for (int r = 0; r < 4; ++r) {
                    const int m = mb + r;
                    const int b = m >> 11, s = m & (S_-1);
                    C[(((size_t)b*H_ + h)*S_ + s)*HD_ + d] = (bf16_t)acc[i][j][r];
                }
            }
        }
    } else {
        float* __restrict__ C = (float*)p.C[blockIdx.z];
        #pragma unroll
        for (int i = 0; i < 4; ++i) {
            const int mb = m0 + wm*64 + i*16 + quad*4;
            #pragma unroll
            for (int j = 0; j < 4; ++j) {
                const int n = n0 + wn*64 + j*16 + l16;
                #pragma unroll
                for (int r = 0; r < 4; ++r)
                    C[(size_t)(mb + r)*HDIM + n] = acc[i][j][r];
            }
        }
    }
}

// ------ RMSNorm + RoPE2D in place on q,k; v normed + transposed to [bh][d][s]
// q additionally scaled by log2(e) so flash can use raw v_exp_f32 (exp2).
__global__ __launch_bounds__(256) void norm_rope(
    bf16_t* __restrict__ qb, bf16_t* __restrict__ kb,
    const bf16_t* __restrict__ vb, bf16_t* __restrict__ vt,
    const float* __restrict__ cs, const float* __restrict__ sn,
    const float* __restrict__ qscale, const float* __restrict__ kscale) {
    __shared__ bf16_t lv[64*65];
    const int bh = blockIdx.y;
    const int b  = bh >> 4;
    const int s0 = blockIdx.x * 64;
    const int t = threadIdx.x;
    const int wave = t >> 6;
    const int lane = t & 63;
    const float qsc = qscale[lane] * LOG2E;
    const float ksc = kscale[lane];
    const float sg = (lane & 16) ? 1.f : -1.f;

    for (int i = 0; i < 16; ++i) {
        const int s = s0 + wave*16 + i;
        const size_t addr = ((size_t)bh*S_ + s)*HD_ + lane;
        const float q = (float)qb[addr];
        const float k = (float)kb[addr];
        const float v = (float)vb[addr];
        float sq = q*q, sk = k*k, sv = v*v;
        #pragma unroll
        for (int m = 32; m; m >>= 1) {
            sq += __shfl_xor(sq, m);
            sk += __shfl_xor(sk, m);
            sv += __shfl_xor(sv, m);
        }
        float qv = q * rsqrtf(sq*(1.f/64.f) + 1e-6f) * qsc;
        float kv = k * rsqrtf(sk*(1.f/64.f) + 1e-6f) * ksc;
        const float vv = v * rsqrtf(sv*(1.f/64.f) + 1e-6f);
        const size_t ci = ((size_t)b*S_ + s)*HD_ + lane;
        const float c = cs[ci];
        const float sn_ = sn[ci];
        const float qo = __shfl_xor(qv, 16);
        const float ko = __shfl_xor(kv, 16);
        qv = qv*c + sg*qo*sn_;
        kv = kv*c + sg*ko*sn_;
        qb[addr] = (bf16_t)qv;
        kb[addr] = (bf16_t)kv;
        lv[(wave*16 + i)*65 + lane] = (bf16_t)vv;
    }
    __syncthreads();
    const int d = t >> 2;
    const int sc = (t & 3) * 16;
    bf16x8 o0, o1;
    #pragma unroll
    for (int e = 0; e < 8; ++e) {
        o0[e] = lv[(sc + e)*65 + d];
        o1[e] = lv[(sc + 8 + e)*65 + d];
    }
    bf16_t* dst = &vt[((size_t)bh*HD_ + d)*S_ + s0 + sc];
    *(bf16x8*)(dst)     = o0;
    *(bf16x8*)(dst + 8) = o1;
}

// ---------------- flash attention v4 -------------------------------------
// 512 thr = 8 waves, each wave owns 32 q-rows (2 row-blocks) -> K/V fragment
// reads amortized 2x. BQ=256, 64-key tiles, register-prefetch double buffer,
// no-max exp2 softmax (C seeded at -46), L via ones-column MFMA.
__global__ __launch_bounds__(512, 4) void flash_attn(
    const bf16_t* __restrict__ qn, const bf16_t* __restrict__ kn,
    const bf16_t* __restrict__ vt, bf16_t* __restrict__ attn_out) {
    __shared__ bf16_t lK[64*72];     // [key][d]
    __shared__ bf16_t lV[64*72];     // [d][key]
    __shared__ bf16_t lP[8*32*76];   // per-wave [32 q][64 key]

    const int bh = blockIdx.y;
    const int b  = bh >> 4;
    const int h  = bh & 15;
    const int q0 = blockIdx.x * 256;
    const int t = threadIdx.x;
    const int wave = t >> 6;
    const int lane = t & 63;
    const int l16 = lane & 15;
    const int quad = lane >> 4;
    const floatx4 finit = {-46.f, -46.f, -46.f, -46.f};

    const bf16_t* Q  = qn + (size_t)bh * S_ * HD_;
    const bf16_t* K  = kn + (size_t)bh * S_ * HD_;
    const bf16_t* Vt = vt + (size_t)bh * HD_ * S_;

    // Q fragments: 2 row-blocks x 2 k-halves
    bf16x8 qf[2][2];
    #pragma unroll
    for (int rb = 0; rb < 2; ++rb) {
        const int qrow = q0 + wave*32 + rb*16 + l16;
        qf[rb][0] = *(const bf16x8*)(&Q[(size_t)qrow*HD_ + quad*8]);
        qf[rb][1] = *(const bf16x8*)(&Q[(size_t)qrow*HD_ + 32 + quad*8]);
    }

    bf16x8 onesf;
    {
        const bf16_t oz = (l16 == 0) ? (bf16_t)1.f : (bf16_t)0.f;
        #pragma unroll
        for (int e = 0; e < 8; ++e) onesf[e] = oz;
    }

    floatx4 accO[2][4] = {};
    floatx4 accL[2] = {};

    bf16_t* lPw = &lP[wave*32*76];

    const int srow = t >> 3;
    const int skc  = (t & 7) * 8;

    bf16x8 kpre = *(const bf16x8*)(&K[(size_t)srow*HD_ + skc]);
    bf16x8 vpre = *(const bf16x8*)(&Vt[(size_t)srow*S_ + skc]);

    for (int kt = 0; kt < S_; kt += 64) {
        __syncthreads();
        *(bf16x8*)(&lK[srow*72 + skc]) = kpre;
        *(bf16x8*)(&lV[srow*72 + skc]) = vpre;
        __syncthreads();
        {
            const int ktn = (kt + 64 < S_) ? kt + 64 : kt;
            kpre = *(const bf16x8*)(&K[(size_t)(ktn+srow)*HD_ + skc]);
            vpre = *(const bf16x8*)(&Vt[(size_t)srow*S_ + ktn + skc]);
        }

        // S = Q K^T - 46; P = exp2(S) -> LDS. K-frags read once per ct,
        // reused by both row-blocks.
        #pragma unroll
        for (int ct = 0; ct < 4; ++ct) {
            const bf16x8 kf0 = *(const bf16x8*)(&lK[(ct*16+l16)*72 + quad*8]);
            const bf16x8 kf1 = *(const bf16x8*)(&lK[(ct*16+l16)*72 + 32 + quad*8]);
            #pragma unroll
            for (int rb = 0; rb < 2; ++rb) {
                floatx4 s = MFMA16(qf[rb][0], kf0, finit);
                s = MFMA16(qf[rb][1], kf1, s);
                #pragma unroll
                for (int r = 0; r < 4; ++r)
                    lPw[(rb*16 + quad*4 + r)*76 + ct*16 + l16] =
                        (bf16_t)__builtin_amdgcn_exp2f(s[r]);
            }
        }

        // O += P V ; L += P * ones. V-frags read once per dt, reused by both rbs.
        bf16x8 pa[2][2];
        #pragma unroll
        for (int rb = 0; rb < 2; ++rb) {
            pa[rb][0] = *(const bf16x8*)(&lPw[(rb*16 + l16)*76 + quad*8]);
            pa[rb][1] = *(const bf16x8*)(&lPw[(rb*16 + l16)*76 + 32 + quad*8]);
        }
        #pragma unroll
        for (int dt = 0; dt < 4; ++dt) {
            const bf16x8 vb0 = *(const bf16x8*)(&lV[(dt*16+l16)*72 + quad*8]);
            const bf16x8 vb1 = *(const bf16x8*)(&lV[(dt*16+l16)*72 + 32 + quad*8]);
            #pragma unroll
            for (int rb = 0; rb < 2; ++rb) {
                accO[rb][dt] = MFMA16(pa[rb][0], vb0, accO[rb][dt]);
                accO[rb][dt] = MFMA16(pa[rb][1], vb1, accO[rb][dt]);
            }
        }
        #pragma unroll
        for (int rb = 0; rb < 2; ++rb) {
            accL[rb] = MFMA16(pa[rb][0], onesf, accL[rb]);
            accL[rb] = MFMA16(pa[rb][1], onesf, accL[rb]);
        }
    }

    // epilogue: l for row quad*4+r sits at col 0 -> lane quad*16; broadcast
    #pragma unroll
    for (int rb = 0; rb < 2; ++rb) {
        #pragma unroll
        for (int r = 0; r < 4; ++r) {
            const float lr = __shfl(accL[rb][r], lane & 48);
            const float inv = 1.f / lr;
            const int srw = q0 + wave*32 + rb*16 + quad*4 + r;
            #pragma unroll
            for (int dt = 0; dt < 4; ++dt) {
                attn_out[((size_t)b*S_ + srw)*HDIM + h*HD_ + dt*16 + l16] =
                    (bf16_t)(accO[rb][dt][r] * inv);
            }
        }
    }
}

extern "C" void kernel_launch(void* const* d_in, const int* in_sizes, int n_in,
                              void* d_out, int out_size, void* d_ws, size_t ws_size,
                              hipStream_t stream) {
    (void)in_sizes; (void)n_in; (void)out_size; (void)ws_size;
    const float* X  = (const float*)d_in[0];
    const float* cs = (const float*)d_in[1];
    const float* sn = (const float*)d_in[2];
    const float* wq = (const float*)d_in[4];
    const float* wk = (const float*)d_in[5];
    const float* wv = (const float*)d_in[6];
    const float* wo = (const float*)d_in[7];
    const float* qs = (const float*)d_in[8];
    const float* ks = (const float*)d_in[9];
    float* out = (float*)d_out;

    const size_t PROJ = (size_t)NTOK * HDIM;
    const size_t WSZ  = (size_t)HDIM * D_;
    bf16_t* ws   = (bf16_t*)d_ws;
    bf16_t* Xb   = ws;                 // dead after gemm1 -> reused as vt
    bf16_t* wqb  = ws + PROJ;
    bf16_t* wkb  = wqb + WSZ;
    bf16_t* wvb  = wkb + WSZ;
    bf16_t* wob  = wvb + WSZ;
    bf16_t* qb   = wob + WSZ;
    bf16_t* kb   = qb + PROJ;
    bf16_t* vb   = kb + PROJ;          // dead after norm_rope -> reused as attn
    bf16_t* vt   = Xb;
    bf16_t* attn = vb;                 // total ws: 72 MB

    Cvt5 cp;
    cp.s[0] = X;  cp.d[0] = Xb;  cp.n4[0] = (int)(PROJ/4);
    cp.s[1] = wq; cp.d[1] = wqb; cp.n4[1] = (int)(WSZ/4);
    cp.s[2] = wk; cp.d[2] = wkb; cp.n4[2] = (int)(WSZ/4);
    cp.s[3] = wv; cp.d[3] = wvb; cp.n4[3] = (int)(WSZ/4);
    cp.s[4] = wo; cp.d[4] = wob; cp.n4[4] = (int)(WSZ/4);
    cvt5<<<dim3(1024, 5), 256, 0, stream>>>(cp);

    GemmPtrs g1;
    g1.A[0] = Xb;  g1.A[1] = Xb;  g1.A[2] = Xb;
    g1.W[0] = wqb; g1.W[1] = wkb; g1.W[2] = wvb;
    g1.C[0] = qb;  g1.C[1] = kb;  g1.C[2] = vb;
    gemm_nt<1><<<dim3(HDIM/128, NTOK/128, 3), 256, 0, stream>>>(g1, D_);

    norm_rope<<<dim3(S_/64, B_*H_), 256, 0, stream>>>(qb, kb, vb, vt, cs, sn, qs, ks);

    flash_attn<<<dim3(S_/256, B_*H_), 512, 0, stream>>>(qb, kb, vt, attn);

    GemmPtrs g2;
    g2.A[0] = attn; g2.W[0] = wob; g2.C[0] = out;
    g2.A[1] = attn; g2.W[1] = wob; g2.C[1] = out;
    g2.A[2] = attn; g2.W[2] = wob; g2.C[2] = out;
    gemm_nt<2><<<dim3(HDIM/128, NTOK/128, 1), 256, 0, stream>>>(g2, HDIM);
}